// Round 18
// baseline (102.832 us; speedup 1.0000x reference)
//
#include <hip/hip_runtime.h>
#include <math.h>

#define NN 8192
#define IN_F 128
#define OUT_F 64
#define NEG_SLOPE 0.01f
#define CAP 256      // max stored neighbors per row (avg ~33, tail << CAP)

typedef int v4i __attribute__((ext_vector_type(4)));

// Tiny: zero the per-row degree/append cursors (must precede all appends).
__global__ void zero_deg(int* __restrict__ degG) {
    const int g = blockIdx.x * 256 + threadIdx.x;
    if (g < NN) degG[g] = 0;
}

// Mega kernel, SCAN FIRST (blocks 0..NN-1), LINEAR LAST (blocks NN..NN+1023).
// Scan branch (R13 verbatim): row i, cols >= i, ragged depth-2 stream; hits
// append j to row i's global list, j>i mirror-appends i into row j's.
// Linear branch (FIXED vs R16's failed version): BLOCK-cooperative per row.
// All 256 threads = 64 quads; quad q owns feature f=q, lane s4=t&3 owns
// k-slice [s4*32, s4*32+32). Quad shfl_xor -> full 128-dot in every quad
// lane; s4==0 lanes store z. Per-wave shfl_down tree -> 16-feature partials
// of zi/zj into LDS[row][wave]; one barrier; threads 0..7 finalize ev/dv.
__global__ __launch_bounds__(256, 8) void mega(
    const float* __restrict__ A, const float* __restrict__ X,
    const float* __restrict__ W, const float* __restrict__ b,
    const float* __restrict__ a1, const float* __restrict__ a2,
    float* __restrict__ z, float* __restrict__ ev, float* __restrict__ dv,
    int* __restrict__ degG, int* __restrict__ nbrG)
{
    __shared__ float pw1[8][4], pw2[8][4];   // 256 B: row x wave partials
    const int t = threadIdx.x;

    if (blockIdx.x < NN) {
        // ---- Scan branch: row i, columns >= i (R13-proven) ----
        const int i = blockIdx.x;
        const v4i* __restrict__ Arow = reinterpret_cast<const v4i*>(A + (size_t)i * NN);
        const int s0 = i >> 2;             // first int4 containing column i

#define APPEND(J)                                                             \
        {                                                                     \
            int k = atomicAdd(&degG[i], 1);                                   \
            if (k < CAP) nbrG[(size_t)i * CAP + k] = (J);                     \
            if ((J) > i) {                                                    \
                int k2 = atomicAdd(&degG[(J)], 1);                            \
                if (k2 < CAP) nbrG[(size_t)(J) * CAP + k2] = i;               \
            }                                                                 \
        }

        int s = s0 + t;
        v4i cur = {0, 0, 0, 0};
        if (s < NN / 4) cur = Arow[s];

        while (s < NN / 4) {
            const int sn = s + 256;
            v4i nxt = {0, 0, 0, 0};
            if (sn < NN / 4) nxt = Arow[sn];   // depth-2: next chunk in flight
            if (((cur.x | cur.y) | (cur.z | cur.w)) != 0) {   // rare (~33/row)
                const int j0 = s * 4;
                if (cur.x != 0 && j0 + 0 >= i) APPEND(j0 + 0)
                if (cur.y != 0 && j0 + 1 >= i) APPEND(j0 + 1)
                if (cur.z != 0 && j0 + 2 >= i) APPEND(j0 + 2)
                if (cur.w != 0 && j0 + 3 >= i) APPEND(j0 + 3)
            }
            cur = nxt; s = sn;
        }
#undef APPEND
        return;
    }

    // ---- Linear branch: 8 rows per block, block-cooperative ----
    const int blk = blockIdx.x - NN;       // 0..1023
    const int wid = t >> 6, lane = t & 63;
    const int f = t >> 2;                  // output feature 0..63 (block-wide)
    const int s4 = t & 3;                  // k-slice 0..3 (32 dims each)

    // W fragment: thread's own 128-B chunk W[f][s4*32 .. s4*32+31].
    float4 w4[8];
    {
        const float4* Wv = reinterpret_cast<const float4*>(W) + ((size_t)f * 32 + s4 * 8);
#pragma unroll
        for (int q = 0; q < 8; ++q) w4[q] = Wv[q];
    }
    const float bf = b[f];
    const float a1f = a1[f], a2f = a2[f];
    const float qm = (s4 == 0) ? 1.f : 0.f;   // count each feature once

#pragma unroll
    for (int r = 0; r < 8; ++r) {
        const int i = blk * 8 + r;
        const float4* xr = reinterpret_cast<const float4*>(X + (size_t)i * IN_F) + s4 * 8;
        float u = 0.f;
#pragma unroll
        for (int q = 0; q < 8; ++q) {
            const float4 xv = xr[q];       // 4 distinct addrs/wave: broadcast
            u = fmaf(w4[q].x, xv.x, u);
            u = fmaf(w4[q].y, xv.y, u);
            u = fmaf(w4[q].z, xv.z, u);
            u = fmaf(w4[q].w, xv.w, u);
        }
        // quad reduce: all 4 lanes of the quad get the full 128-dot
        u += __shfl_xor(u, 1, 64);
        u += __shfl_xor(u, 2, 64);
        const float zval = u + bf;
        if (s4 == 0) z[(size_t)i * OUT_F + f] = zval;

        // zi/zj partials: quad-lane-0 contributes its feature once; wave tree
        // sums the wave's 16 features -> lane 0.
        float p1 = qm * a1f * zval;
        float p2 = qm * a2f * zval;
        p1 += __shfl_down(p1, 32, 64); p2 += __shfl_down(p2, 32, 64);
        p1 += __shfl_down(p1, 16, 64); p2 += __shfl_down(p2, 16, 64);
        p1 += __shfl_down(p1,  8, 64); p2 += __shfl_down(p2,  8, 64);
        p1 += __shfl_down(p1,  4, 64); p2 += __shfl_down(p2,  4, 64);
        if (lane == 0) { pw1[r][wid] = p1; pw2[r][wid] = p2; }
    }
    __syncthreads();

    if (t < 8) {
        const int i = blk * 8 + t;
        const float zi = pw1[t][0] + pw1[t][1] + pw1[t][2] + pw1[t][3];
        const float zj = pw2[t][0] + pw2[t][1] + pw2[t][2] + pw2[t][3];
        const float s1 = zi;
        const float s2 = zi + zj;
        const float l1 = s1 > 0.f ? s1 : NEG_SLOPE * s1;
        const float l2 = s2 > 0.f ? s2 : NEG_SLOPE * s2;
        ev[i] = expf(l1);
        dv[i] = expf(l2);
    }
}

// Gather + finalize (unchanged, proven). One wave per row.
//   S = (deg-1)*e + d ;  out = relu( z_i*(1+(e-d)/S) - (e/S)*sumNbr ).
__global__ __launch_bounds__(256, 8) void k2b_gather(
    const int* __restrict__ degG, const int* __restrict__ nbrG,
    const float* __restrict__ z, const float* __restrict__ ev,
    const float* __restrict__ dv, float* __restrict__ out)
{
    const int t = threadIdx.x;
    const int wid = t >> 6, lane = t & 63;
    const int i = blockIdx.x * 4 + wid;

    const int cnt0 = degG[i];
    const int cnt = cnt0 < CAP ? cnt0 : CAP;
    const int* rowl = nbrG + (size_t)i * CAP;

    float acc = 0.f;
    for (int k0 = 0; k0 < cnt; k0 += 64) {
        const int m = (cnt - k0) < 64 ? (cnt - k0) : 64;
        const int jv = (lane < m) ? rowl[k0 + lane] : 0;
        int kk = 0;
        for (; kk + 4 <= m; kk += 4) {
            const int j0 = __shfl(jv, kk + 0, 64);
            const int j1 = __shfl(jv, kk + 1, 64);
            const int j2 = __shfl(jv, kk + 2, 64);
            const int j3 = __shfl(jv, kk + 3, 64);
            const float z0 = z[(size_t)j0 * OUT_F + lane];
            const float z1 = z[(size_t)j1 * OUT_F + lane];
            const float z2 = z[(size_t)j2 * OUT_F + lane];
            const float z3 = z[(size_t)j3 * OUT_F + lane];
            acc += (z0 + z1) + (z2 + z3);
        }
        for (; kk < m; ++kk) {
            const int j = __shfl(jv, kk, 64);
            acc += z[(size_t)j * OUT_F + lane];
        }
    }

    const float degT = (float)cnt0;
    const float e = ev[i], d = dv[i];
    const float S = (degT - 1.f) * e + d;
    const float zif = z[(size_t)i * OUT_F + lane];
    const float h = zif * (1.f + (e - d) / S) - (e / S) * acc;
    out[(size_t)i * OUT_F + lane] = h > 0.f ? h : 0.f;
}

extern "C" void kernel_launch(void* const* d_in, const int* in_sizes, int n_in,
                              void* d_out, int out_size, void* d_ws, size_t ws_size,
                              hipStream_t stream) {
    const float* X  = (const float*)d_in[0];   // [8192,128]
    const float* A  = (const float*)d_in[1];   // [8192,8192]
    const float* W  = (const float*)d_in[2];   // [64,128]
    const float* b  = (const float*)d_in[3];   // [64]
    const float* a1 = (const float*)d_in[4];   // [64]
    const float* a2 = (const float*)d_in[5];   // [64]
    float* out = (float*)d_out;                // [8192,64]

    char* ws = (char*)d_ws;
    float* z    = (float*)ws;                                   // 2 MB
    float* ev   = (float*)(ws + (size_t)NN * OUT_F * 4);        // 32 KB
    float* dv   = ev + NN;                                      // 32 KB
    int*   degG = (int*)(dv + NN);                              // 32 KB
    int*   nbrG = degG + NN;                                    // 8 MB

    zero_deg<<<NN / 256, 256, 0, stream>>>(degG);
    mega<<<NN + 1024, 256, 0, stream>>>(A, X, W, b, a1, a2, z, ev, dv, degG, nbrG);
    k2b_gather<<<NN / 4, 256, 0, stream>>>(degG, nbrG, z, ev, dv, out);
}

// Round 19
// 61.531 us; speedup vs baseline: 1.6712x; 1.6712x over previous
//
#include <hip/hip_runtime.h>
#include <math.h>

#define NN 8192
#define IN_F 128
#define OUT_F 64
#define NEG_SLOPE 0.01f
#define K1_ROWS 8    // rows of z per block in k1 -> 1024 blocks
#define CAP 256      // max stored neighbors per row (avg ~33, tail << CAP)

typedef int v4i __attribute__((ext_vector_type(4)));

// Kernel 1: z = X @ W^T + b ; per-row zi = dot(a1,z_i), zj = dot(a2,z_i);
// e_i = exp(lrelu(zi)), d_i = exp(lrelu(zi+zj)). Also zeroes degG.
__global__ __launch_bounds__(256, 4) void k1_linear(
    const float* __restrict__ X, const float* __restrict__ W,
    const float* __restrict__ b, const float* __restrict__ a1,
    const float* __restrict__ a2, float* __restrict__ z,
    float* __restrict__ ev, float* __restrict__ dv, int* __restrict__ degG)
{
    __shared__ float Wl[OUT_F * 129];        // stride 129 -> conflict-free
    __shared__ float xs[K1_ROWS * IN_F];
    const int t = threadIdx.x;
    const int blk = blockIdx.x;

    // Zero the degree counters (1024 blocks x 256 threads >= NN).
    const int gid = blk * 256 + t;
    if (gid < NN) degG[gid] = 0;

    for (int idx = t; idx < OUT_F * IN_F; idx += 256) {
        int f = idx >> 7, k = idx & 127;
        Wl[f * 129 + k] = W[idx];
    }
    {
        const float4* Xv = reinterpret_cast<const float4*>(X + (size_t)blk * (K1_ROWS * IN_F));
        float4* xsv = reinterpret_cast<float4*>(xs);
        if (t < K1_ROWS * IN_F / 4) xsv[t] = Xv[t];
    }
    __syncthreads();

    const int wid = t >> 6;
    const int lane = t & 63;    // output feature
    const float bias = b[lane];
    const float a1f = a1[lane], a2f = a2[lane];

#pragma unroll
    for (int r2 = 0; r2 < 2; ++r2) {
        const int row = wid * 2 + r2;
        float acc = 0.f;
#pragma unroll 8
        for (int k = 0; k < IN_F; ++k)
            acc = fmaf(xs[row * IN_F + k], Wl[lane * 129 + k], acc);
        const float zval = acc + bias;
        const int i = blk * K1_ROWS + row;
        z[i * OUT_F + lane] = zval;

        float p1 = a1f * zval;
        float p2 = a2f * zval;
#pragma unroll
        for (int off = 32; off > 0; off >>= 1) {
            p1 += __shfl_down(p1, off, 64);
            p2 += __shfl_down(p2, off, 64);
        }
        if (lane == 0) {
            const float s1 = p1;
            const float s2 = p1 + p2;
            const float l1 = s1 > 0.f ? s1 : NEG_SLOPE * s1;
            const float l2 = s2 > 0.f ? s2 : NEG_SLOPE * s2;
            ev[i] = expf(l1);
            dv[i] = expf(l2);
        }
    }
}

// Kernel 2a: SYMMETRY-HALVED stream. A is symmetric (reference sets both
// [u,v] and [v,u], plus diagonal), so block i scans only columns j >= i
// (~134 MB total instead of 268). Each hit j>=i appends j to row i's global
// list; hits j>i also mirror-append i to row j's list. deg counters double
// as append cursors. List order is nondeterministic (atomic append) but the
// downstream sum is order-insensitive to ~1e-5.
__global__ __launch_bounds__(256, 8) void k2a_sym(
    const float* __restrict__ A, int* __restrict__ degG, int* __restrict__ nbrG)
{
    const int i = blockIdx.x;
    const int t = threadIdx.x;
    const v4i* __restrict__ Arow = reinterpret_cast<const v4i*>(A + (size_t)i * NN);
    const int s0 = i >> 2;             // first int4 index containing column i

#define APPEND(J)                                                             \
    {                                                                         \
        int k = atomicAdd(&degG[i], 1);                                       \
        if (k < CAP) nbrG[(size_t)i * CAP + k] = (J);                         \
        if ((J) > i) {                                                        \
            int k2 = atomicAdd(&degG[(J)], 1);                                \
            if (k2 < CAP) nbrG[(size_t)(J) * CAP + k2] = i;                    \
        }                                                                     \
    }

    int s = s0 + t;
    v4i cur = {0, 0, 0, 0};
    if (s < NN / 4) cur = Arow[s];

    while (s < NN / 4) {
        const int sn = s + 256;
        v4i nxt = {0, 0, 0, 0};
        if (sn < NN / 4) nxt = Arow[sn];   // depth-2: next chunk in flight
        if (((cur.x | cur.y) | (cur.z | cur.w)) != 0) {   // rare (~33/row)
            const int j0 = s * 4;
            if (cur.x != 0 && j0 + 0 >= i) APPEND(j0 + 0)
            if (cur.y != 0 && j0 + 1 >= i) APPEND(j0 + 1)
            if (cur.z != 0 && j0 + 2 >= i) APPEND(j0 + 2)
            if (cur.w != 0 && j0 + 3 >= i) APPEND(j0 + 3)
        }
        cur = nxt; s = sn;
    }
#undef APPEND
}

// Kernel 2b: gather + finalize. One wave per row (4 rows/block). Read the
// row's neighbor list (includes the diagonal entry i), broadcast each j via
// shuffle, gather z[j,:] (256 B coalesced, L2-resident), 4-wide unrolled.
//   S = (deg-1)*e + d ;  out = relu( z_i*(1+(e-d)/S) - (e/S)*sumNbr ).
__global__ __launch_bounds__(256, 8) void k2b_gather(
    const int* __restrict__ degG, const int* __restrict__ nbrG,
    const float* __restrict__ z, const float* __restrict__ ev,
    const float* __restrict__ dv, float* __restrict__ out)
{
    const int t = threadIdx.x;
    const int wid = t >> 6, lane = t & 63;
    const int i = blockIdx.x * 4 + wid;

    const int cnt0 = degG[i];
    const int cnt = cnt0 < CAP ? cnt0 : CAP;
    const int* rowl = nbrG + (size_t)i * CAP;

    float acc = 0.f;
    for (int k0 = 0; k0 < cnt; k0 += 64) {
        const int m = (cnt - k0) < 64 ? (cnt - k0) : 64;
        const int jv = (lane < m) ? rowl[k0 + lane] : 0;
        int kk = 0;
        for (; kk + 4 <= m; kk += 4) {
            const int j0 = __shfl(jv, kk + 0, 64);
            const int j1 = __shfl(jv, kk + 1, 64);
            const int j2 = __shfl(jv, kk + 2, 64);
            const int j3 = __shfl(jv, kk + 3, 64);
            const float z0 = z[(size_t)j0 * OUT_F + lane];
            const float z1 = z[(size_t)j1 * OUT_F + lane];
            const float z2 = z[(size_t)j2 * OUT_F + lane];
            const float z3 = z[(size_t)j3 * OUT_F + lane];
            acc += (z0 + z1) + (z2 + z3);
        }
        for (; kk < m; ++kk) {
            const int j = __shfl(jv, kk, 64);
            acc += z[(size_t)j * OUT_F + lane];
        }
    }

    const float degT = (float)cnt0;
    const float e = ev[i], d = dv[i];
    const float S = (degT - 1.f) * e + d;
    const float zif = z[(size_t)i * OUT_F + lane];
    const float h = zif * (1.f + (e - d) / S) - (e / S) * acc;
    out[(size_t)i * OUT_F + lane] = h > 0.f ? h : 0.f;
}

extern "C" void kernel_launch(void* const* d_in, const int* in_sizes, int n_in,
                              void* d_out, int out_size, void* d_ws, size_t ws_size,
                              hipStream_t stream) {
    const float* X  = (const float*)d_in[0];   // [8192,128]
    const float* A  = (const float*)d_in[1];   // [8192,8192]
    const float* W  = (const float*)d_in[2];   // [64,128]
    const float* b  = (const float*)d_in[3];   // [64]
    const float* a1 = (const float*)d_in[4];   // [64]
    const float* a2 = (const float*)d_in[5];   // [64]
    float* out = (float*)d_out;                // [8192,64]

    char* ws = (char*)d_ws;
    float* z    = (float*)ws;                                   // 2 MB
    float* ev   = (float*)(ws + (size_t)NN * OUT_F * 4);        // 32 KB
    float* dv   = ev + NN;                                      // 32 KB
    int*   degG = (int*)(dv + NN);                              // 32 KB
    int*   nbrG = degG + NN;                                    // 8 MB

    k1_linear<<<NN / K1_ROWS, 256, 0, stream>>>(X, W, b, a1, a2, z, ev, dv, degG);
    k2a_sym<<<NN, 256, 0, stream>>>(A, degG, nbrG);
    k2b_gather<<<NN / 4, 256, 0, stream>>>(degG, nbrG, z, ev, dv, out);
}